// Round 7
// baseline (336.697 us; speedup 1.0000x reference)
//
#include <hip/hip_runtime.h>
#include <hip/hip_bf16.h>

typedef unsigned long long u64;
typedef unsigned int u32;

#define LOG2E 1.44269504088896340736f
#define LN2   0.69314718055994530942f

// ---------- fast math ----------
__device__ __forceinline__ float fexp2(float x) { return __builtin_amdgcn_exp2f(x); }
__device__ __forceinline__ float flog2(float x) { return __builtin_amdgcn_logf(x); }
__device__ __forceinline__ float frcp(float x)  { return __builtin_amdgcn_rcpf(x); }
__device__ __forceinline__ float fsigmoid(float x) {
    float e = fexp2(-fabsf(x) * LOG2E);
    float r = frcp(1.0f + e);
    return x >= 0.0f ? r : e * r;
}
__device__ __forceinline__ float keyval(u64 k) { return __uint_as_float((u32)(k >> 32)); }

__device__ __forceinline__ float iou_xyxy(float ax1, float ay1, float ax2, float ay2,
                                          float bx1, float by1, float bx2, float by2) {
    float ltx = fmaxf(ax1, bx1), lty = fmaxf(ay1, by1);
    float rbx = fminf(ax2, bx2), rby = fminf(ay2, by2);
    float w = fmaxf(rbx - ltx, 0.0f), h = fmaxf(rby - lty, 0.0f);
    float inter = w * h;
    float areaA = (ax2 - ax1) * (ay2 - ay1);
    float areaB = (bx2 - bx1) * (by2 - by1);
    return inter / (areaA + areaB - inter);
}

__device__ __forceinline__ void csw(u64& a, u64& b) { if (a < b) { u64 t = a; a = b; b = t; } }

// Per-block per-row top-15 tournament (see round 5). fkey: [16][65] u64 LDS.
__device__ __forceinline__ void row_top15(const u64* fkey, u64* cand, size_t rowbase,
                                          int blk, int NBLK, int tid) {
    int o = tid >> 4, l16 = tid & 15;
    const u64* rk = fkey + o * 65;
    u64 k0 = rk[l16 * 4], k1 = rk[l16 * 4 + 1], k2 = rk[l16 * 4 + 2], k3 = rk[l16 * 4 + 3];
    csw(k0, k1); csw(k2, k3); csw(k0, k2); csw(k1, k3); csw(k1, k2);
    u64 w = 0;
    #pragma unroll
    for (int j = 0; j < 15; j++) {
        u64 m = k0;
        #pragma unroll
        for (int s = 8; s >= 1; s >>= 1) { u64 t = __shfl_xor(m, s, 16); if (t > m) m = t; }
        if (k0 == m) { k0 = k1; k1 = k2; k2 = k3; k3 = 0; }
        if (l16 == j) w = m;
    }
    if (l16 < 15) {
        u64* out = cand + ((rowbase + (size_t)o) * (size_t)NBLK + blk) * 15;
        out[l16] = w;
    }
}

// ---------- K0 ----------
__global__ void k_zero(double* accC, double* accL, double* accR, unsigned int* posCount) {
    if (threadIdx.x == 0) { *accC = 0.0; *accL = 0.0; *accR = 0.0; *posCount = 0u; }
}

// ---------- K1: reg path -> ovkey base + per-block top15 candidates ----------
__global__ __launch_bounds__(256) void k_reg(
        const float* __restrict__ loc, const float* __restrict__ priors,
        const float* __restrict__ truths, u64* __restrict__ ovkey,
        u64* __restrict__ cand, int P, int NBLK) {
    int n = blockIdx.y, p0 = blockIdx.x * 64, tid = threadIdx.x;
    __shared__ float strt[64];
    __shared__ u64 fkey[16 * 65];
    if (tid < 64) strt[tid] = truths[n * 64 + tid];
    __syncthreads();
    int r = tid >> 2, sub = tid & 3, p = p0 + r;
    bool act = p < P;
    float vv[4] = {0, 0, 0, 0};
    u64 mykey = 0;
    if (act) {
        float4 pr = *(const float4*)(priors + (size_t)p * 4);
        float4 l  = *(const float4*)(loc + ((size_t)n * P + p) * 4);
        float cx = pr.x + l.x * 0.1f * pr.z;
        float cy = pr.y + l.y * 0.1f * pr.w;
        float w  = pr.z * fexp2(l.z * 0.2f * LOG2E);
        float h  = pr.w * fexp2(l.w * 0.2f * LOG2E);
        float bx1 = cx - w * 0.5f, by1 = cy - h * 0.5f;
        float bx2 = cx + w * 0.5f, by2 = cy + h * 0.5f;
        #pragma unroll
        for (int jj = 0; jj < 4; jj++) {
            int o = sub * 4 + jj;
            float v = iou_xyxy(strt[o * 4], strt[o * 4 + 1], strt[o * 4 + 2], strt[o * 4 + 3],
                               bx1, by1, bx2, by2);
            vv[jj] = v;
            u64 kk = ((u64)__float_as_uint(v) << 32) | (u32)(~(u32)o);
            if (kk > mykey) mykey = kk;
        }
    }
    { u64 t = __shfl_xor(mykey, 1, 64); if (t > mykey) mykey = t;
      t = __shfl_xor(mykey, 2, 64); if (t > mykey) mykey = t; }
    float m = keyval(mykey);
    if (act && sub == 0) ovkey[(size_t)n * P + p] = mykey;
    #pragma unroll
    for (int jj = 0; jj < 4; jj++) {
        int o = sub * 4 + jj;
        u64 kk = 0;
        if (act) kk = ((vv[jj] == m) ? ((u64)__float_as_uint(m) << 32) : 0ULL) | (u32)(~(u32)p);
        fkey[o * 65 + r] = kk;
    }
    __syncthreads();
    row_top15(fkey, cand, (size_t)n * 16, blockIdx.x, NBLK, tid);
}

// ---------- K2/K4: merge per-block top15 lists -> global top15, apply boosts ----------
__global__ __launch_bounds__(256) void k_merge_boost(
        const u64* __restrict__ cand, u64* __restrict__ keyarr, int P, int NBLK) {
    extern __shared__ u64 sk[];
    int row = blockIdx.x, tid = threadIdx.x;
    int n = row >> 4, o = row & 15;
    int total = NBLK * 15;
    const u64* src = cand + (size_t)row * total;
    for (int i = tid; i < total; i += 256) sk[i] = src[i];
    __syncthreads();
    int l0 = tid, l1 = tid + 256;
    int h0 = 0, h1 = 0;
    __shared__ u64 wm[4];
    __shared__ u64 selk[15];
    __shared__ int snum;
    for (int j = 0; j < 15; j++) {
        u64 q0 = (l0 < NBLK && h0 < 15) ? sk[l0 * 15 + h0] : 0ULL;
        u64 q1 = (l1 < NBLK && h1 < 15) ? sk[l1 * 15 + h1] : 0ULL;
        u64 pr = q0 > q1 ? q0 : q1;
        u64 m = pr;
        #pragma unroll
        for (int s = 32; s >= 1; s >>= 1) { u64 t = __shfl_xor(m, s, 64); if (t > m) m = t; }
        if ((tid & 63) == 0) wm[tid >> 6] = m;
        __syncthreads();
        m = wm[0]; if (wm[1] > m) m = wm[1]; if (wm[2] > m) m = wm[2]; if (wm[3] > m) m = wm[3];
        if (m != 0ULL) {
            if (q0 == m) h0++; else if (q1 == m) h1++;
        }
        if (tid == 0) selk[j] = m;
        __syncthreads();
    }
    if (tid == 0) {
        float s = 0.0f;
        #pragma unroll
        for (int j = 0; j < 15; j++) s += keyval(selk[j]);
        int np = (int)s; if (np < 1) np = 1;
        snum = np;
    }
    __syncthreads();
    if (tid < 15 && tid < snum) {
        u64 k = selk[tid];
        u32 pidx = ~(u32)(k & 0xFFFFFFFFULL);
        if (pidx < (u32)P) {
            float v = keyval(k) + 3.0f;
            u64 bk = ((u64)__float_as_uint(v) << 32) | (u32)(~(u32)o);
            atomicMax(&keyarr[(size_t)n * P + pidx], bk);
        }
    }
}

// ---------- K3: fused conf pass, no tile staging ----------
// Thread (r,sub) streams its 20 classes directly from global (coalesced: each
// 64B line consumed by 4 lanes in one instruction). Label sigmoids captured
// into sglab[r][o] during the stream via the block-uniform smask branch.
__global__ __launch_bounds__(256) void k_conf(
        const float* __restrict__ conf, const float* __restrict__ priors,
        const float* __restrict__ truths, const int* __restrict__ labels,
        const u64* __restrict__ ovkey, u64* __restrict__ predkey,
        u64* __restrict__ cand, double* __restrict__ accC,
        unsigned int* __restrict__ posCount, int P, int NBLK) {
    int n = blockIdx.y, p0 = blockIdx.x * 64, tid = threadIdx.x;
    __shared__ float strt[64];
    __shared__ int   lab[16];
    __shared__ u32   smask[80];
    __shared__ float sglab[64][17];     // stride 17: conflict-free column access
    __shared__ u64   fkey[16 * 65];
    if (tid < 64) strt[tid] = truths[n * 64 + tid];
    if (tid < 80) smask[tid] = 0u;
    __syncthreads();
    if (tid < 16) {
        int lb = labels[n * 16 + tid];
        lab[tid] = lb;
        atomicOr(&smask[lb], 1u << tid);
    }
    __syncthreads();

    int r = tid >> 2, sub = tid & 3, p = p0 + r;
    bool act = p < P;

    // overlap_t / conf class from ovkey (8B per row, broadcast across subs)
    float movl = 0.0f; int best = 0;
    if (act) {
        u64 k = ovkey[(size_t)n * P + p];
        movl = keyval(k);
        best = (int)(~(u32)(k & 0xFFFFFFFFULL)) & 15;
    }
    float vt = fmaxf(movl - 3.0f, 0.0f);
    int tc = (movl > 1.0f) ? lab[best] : -1;
    unsigned long long bm = __ballot(act && sub == 0 && movl > 3.0f);
    if ((tid & 63) == 0 && bm) atomicAdd(posCount, (u32)__popcll(bm));

    // ---- gfocal stream (global, coalesced) + label sigmoid capture
    float lsum = 0.0f;
    if (act) {
        const float* rowp = conf + ((size_t)n * P + p) * 80 + sub * 4;
        #pragma unroll
        for (int k = 0; k < 5; k++) {
            float4 l4 = *(const float4*)(rowp + k * 16);
            float lvv[4] = {l4.x, l4.y, l4.z, l4.w};
            #pragma unroll
            for (int j = 0; j < 4; j++) {
                int   c  = k * 16 + sub * 4 + j;
                float lg = lvv[j];
                float t  = (c == tc) ? vt : 0.0f;
                float e  = fexp2(-fabsf(lg) * LOG2E);
                float ln1pe = flog2(1.0f + e) * LN2;
                float rc = frcp(1.0f + e);
                float sg = (lg >= 0.0f) ? rc : e * rc;
                float bce = fmaxf(lg, 0.0f) - lg * t + ln1pe;
                float d  = sg - t;
                lsum += d * d * bce;
                u32 m16 = smask[c];
                while (m16) {                  // block-uniform branch
                    int o = __ffs(m16) - 1;
                    sglab[r][o] = sg;
                    m16 &= m16 - 1;
                }
            }
        }
    }
    __syncthreads();

    // ---- pred path: 4 IoUs + 4 sglab reads per sub-lane
    float pv[4] = {0, 0, 0, 0};
    u64 pkey = 0;
    if (act) {
        float4 pr = *(const float4*)(priors + (size_t)p * 4);
        float px1 = pr.x - pr.z * 0.5f, py1 = pr.y - pr.w * 0.5f;
        float px2 = pr.x + pr.z * 0.5f, py2 = pr.y + pr.w * 0.5f;
        #pragma unroll
        for (int jj = 0; jj < 4; jj++) {
            int o = sub * 4 + jj;
            float ov = iou_xyxy(strt[o * 4], strt[o * 4 + 1], strt[o * 4 + 2], strt[o * 4 + 3],
                                px1, py1, px2, py2);
            float pd = 0.0f;
            if (ov > 0.0f) {
                float pc = sglab[r][o];
                pd = fexp2((2.0f - pc) * 0.5f * flog2(ov));
            }
            pv[jj] = pd;
            u64 kk = ((u64)__float_as_uint(pd) << 32) | (u32)(~(u32)o);
            if (kk > pkey) pkey = kk;
        }
    }
    { u64 t = __shfl_xor(pkey, 1, 64); if (t > pkey) pkey = t;
      t = __shfl_xor(pkey, 2, 64); if (t > pkey) pkey = t; }
    float pm = keyval(pkey);
    if (act && sub == 0) predkey[(size_t)n * P + p] = pkey;

    #pragma unroll
    for (int jj = 0; jj < 4; jj++) {
        int o = sub * 4 + jj;
        u64 kk = 0;
        if (act) kk = ((pv[jj] == pm) ? ((u64)__float_as_uint(pm) << 32) : 0ULL) | (u32)(~(u32)p);
        fkey[o * 65 + r] = kk;
    }
    __syncthreads();
    row_top15(fkey, cand, (size_t)n * 16, blockIdx.x, NBLK, tid);

    // ---- block reduce gfocal partials
    #pragma unroll
    for (int s = 32; s > 0; s >>= 1) lsum += __shfl_down(lsum, s, 64);
    __shared__ float wsum[4];
    if ((tid & 63) == 0) wsum[tid >> 6] = lsum;
    __syncthreads();
    if (tid == 0) {
        double tot = (double)wsum[0] + (double)wsum[1] + (double)wsum[2] + (double)wsum[3];
        atomicAdd(accC, tot);
    }
}

// ---------- K5: localization loss from predkey ----------
__global__ __launch_bounds__(256) void k_loss_l(
        const u64* __restrict__ predkey, const float* __restrict__ loc,
        const float* __restrict__ priors, const float* __restrict__ truths,
        double* __restrict__ accL, double* __restrict__ accR, int P) {
    int n = blockIdx.y;
    int p = blockIdx.x * 256 + threadIdx.x;
    __shared__ float strt[64];
    if (threadIdx.x < 64) strt[threadIdx.x] = truths[n * 64 + threadIdx.x];
    __syncthreads();

    float r = 0.0f, contrib = 0.0f;
    if (p < P) {
        u64 k = predkey[(size_t)n * P + p];
        float pt = keyval(k);
        int best = (int)(~(u32)(k & 0xFFFFFFFFULL)) & 15;
        r = fmaxf(pt - 3.0f, 0.0f);
        if (r > 0.0f) {
            const float Bc   = (float)19.085536923187668;
            const float beta = 0.11f;
            float4 pr = *(const float4*)(priors + (size_t)p * 4);
            float tx1 = strt[best * 4],     ty1 = strt[best * 4 + 1];
            float tx2 = strt[best * 4 + 2], ty2 = strt[best * 4 + 3];
            float gcx = ((tx1 + tx2) * 0.5f - pr.x) / (0.1f * pr.z);
            float gcy = ((ty1 + ty2) * 0.5f - pr.y) / (0.1f * pr.w);
            float gw  = flog2((tx2 - tx1) / pr.z) * LN2 / 0.2f;
            float gh  = flog2((ty2 - ty1) / pr.w) * LN2 / 0.2f;
            float4 l  = *(const float4*)(loc + ((size_t)n * P + p) * 4);
            float tgt[4] = {gcx, gcy, gw, gh};
            float lvv[4] = {l.x, l.y, l.z, l.w};
            float s = 0.0f;
            #pragma unroll
            for (int j = 0; j < 4; j++) {
                float diff = fabsf(lvv[j] - tgt[j]);
                float bl;
                if (diff < beta) {
                    bl = 0.5f / Bc * (Bc * diff + 1.0f) * (flog2(1.0f + Bc * diff / beta) * LN2)
                         - 0.5f * diff;
                } else {
                    bl = 1.5f * diff + 1.5f / Bc - 0.5f * beta;
                }
                s += bl;
            }
            contrib = r * s;
        }
    }
    double dl = (double)contrib, dr = (double)r;
    for (int s = 32; s > 0; s >>= 1) { dl += __shfl_down(dl, s, 64); dr += __shfl_down(dr, s, 64); }
    __shared__ double bl_[4], br_[4];
    int wid = threadIdx.x >> 6;
    if ((threadIdx.x & 63) == 0) { bl_[wid] = dl; br_[wid] = dr; }
    __syncthreads();
    if (threadIdx.x == 0) {
        double tl  = bl_[0] + bl_[1] + bl_[2] + bl_[3];
        double tr2 = br_[0] + br_[1] + br_[2] + br_[3];
        atomicAdd(accL, tl);
        atomicAdd(accR, tr2);
    }
}

// ---------- K7: finalize ----------
__global__ void k_final(const double* accC, const double* accL, const double* accR,
                        const unsigned int* posCount, float* out) {
    if (threadIdx.x == 0) {
        unsigned int pc = *posCount;
        double npos = (double)(pc > 0u ? pc : 1u);
        double denom = 4.0 * (*accR);
        out[0] = (float)((*accL) / denom);
        out[1] = (float)((*accC) / npos);
    }
}

extern "C" void kernel_launch(void* const* d_in, const int* in_sizes, int n_in,
                              void* d_out, int out_size, void* d_ws, size_t ws_size,
                              hipStream_t stream) {
    const float* loc    = (const float*)d_in[0];
    const float* conf   = (const float*)d_in[1];
    const float* priors = (const float*)d_in[2];
    const float* truths = (const float*)d_in[3];
    const int*   labels = (const int*)d_in[4];

    int P = in_sizes[2] / 4;                 // 18000
    int N = in_sizes[0] / (P * 4);           // 32
    int NBLK = (P + 63) / 64;                // 282
    // C == 80, O == 16 assumed by kernel tiling

    char* ws = (char*)d_ws;
    double* accC = (double*)ws;
    double* accL = accC + 1;
    double* accR = accC + 2;
    unsigned int* posCount = (unsigned int*)(accC + 3);
    u64* ovkey   = (u64*)(ws + 64);                       // N*P
    u64* predkey = ovkey + (size_t)N * P;                 // N*P
    u64* cand    = predkey + (size_t)N * P;               // N*16*NBLK*15
    float* out = (float*)d_out;

    dim3 blk(256);
    dim3 gridB(NBLK, N);
    dim3 gridL((P + 255) / 256, N);
    size_t mergeLds = (size_t)NBLK * 15 * sizeof(u64);    // 33840 B

    k_zero<<<1, 64, 0, stream>>>(accC, accL, accR, posCount);
    k_reg<<<gridB, blk, 0, stream>>>(loc, priors, truths, ovkey, cand, P, NBLK);
    k_merge_boost<<<N * 16, blk, mergeLds, stream>>>(cand, ovkey, P, NBLK);
    k_conf<<<gridB, blk, 0, stream>>>(conf, priors, truths, labels, ovkey, predkey,
                                      cand, accC, posCount, P, NBLK);
    k_merge_boost<<<N * 16, blk, mergeLds, stream>>>(cand, predkey, P, NBLK);
    k_loss_l<<<gridL, blk, 0, stream>>>(predkey, loc, priors, truths, accL, accR, P);
    k_final<<<1, 1, 0, stream>>>(accC, accL, accR, posCount, out);
}

// Round 8
// 296.939 us; speedup vs baseline: 1.1339x; 1.1339x over previous
//
#include <hip/hip_runtime.h>
#include <hip/hip_bf16.h>

typedef unsigned long long u64;
typedef unsigned int u32;

#define LOG2E 1.44269504088896340736f
#define LN2   0.69314718055994530942f

// ---------- fast math ----------
__device__ __forceinline__ float fexp2(float x) { return __builtin_amdgcn_exp2f(x); }
__device__ __forceinline__ float flog2(float x) { return __builtin_amdgcn_logf(x); }
__device__ __forceinline__ float frcp(float x)  { return __builtin_amdgcn_rcpf(x); }
__device__ __forceinline__ float keyval(u64 k) { return __uint_as_float((u32)(k >> 32)); }

__device__ __forceinline__ float iou_xyxy(float ax1, float ay1, float ax2, float ay2,
                                          float bx1, float by1, float bx2, float by2) {
    float ltx = fmaxf(ax1, bx1), lty = fmaxf(ay1, by1);
    float rbx = fminf(ax2, bx2), rby = fminf(ay2, by2);
    float w = fmaxf(rbx - ltx, 0.0f), h = fmaxf(rby - lty, 0.0f);
    float inter = w * h;
    float areaA = (ax2 - ax1) * (ay2 - ay1);
    float areaB = (bx2 - bx1) * (by2 - by1);
    return inter / (areaA + areaB - inter);
}

__device__ __forceinline__ void csw(u64& a, u64& b) { if (a < b) { u64 t = a; a = b; b = t; } }

// Per-block per-row top-15 tournament. fkey: [16][65] u64 LDS.
__device__ __forceinline__ void row_top15(const u64* fkey, u64* cand, size_t rowbase,
                                          int blk, int NBLK, int tid) {
    int o = tid >> 4, l16 = tid & 15;
    const u64* rk = fkey + o * 65;
    u64 k0 = rk[l16 * 4], k1 = rk[l16 * 4 + 1], k2 = rk[l16 * 4 + 2], k3 = rk[l16 * 4 + 3];
    csw(k0, k1); csw(k2, k3); csw(k0, k2); csw(k1, k3); csw(k1, k2);
    u64 w = 0;
    #pragma unroll
    for (int j = 0; j < 15; j++) {
        u64 m = k0;
        #pragma unroll
        for (int s = 8; s >= 1; s >>= 1) { u64 t = __shfl_xor(m, s, 16); if (t > m) m = t; }
        if (k0 == m) { k0 = k1; k1 = k2; k2 = k3; k3 = 0; }
        if (l16 == j) w = m;
    }
    if (l16 < 15) {
        u64* out = cand + ((rowbase + (size_t)o) * (size_t)NBLK + blk) * 15;
        out[l16] = w;
    }
}

// ---------- K0 ----------
__global__ void k_zero(double* accC, double* accL, double* accR,
                       unsigned int* posCount, u32* pcnt, int N) {
    int t = threadIdx.x;
    if (t == 0) { *accC = 0.0; *accL = 0.0; *accR = 0.0; *posCount = 0u; }
    if (t < N) pcnt[t] = 0u;
}

// ---------- K1: reg path -> ovkey base + per-block top15 candidates ----------
__global__ __launch_bounds__(256) void k_reg(
        const float* __restrict__ loc, const float* __restrict__ priors,
        const float* __restrict__ truths, u64* __restrict__ ovkey,
        u64* __restrict__ cand, int P, int NBLK) {
    int n = blockIdx.y, p0 = blockIdx.x * 64, tid = threadIdx.x;
    __shared__ float strt[64];
    __shared__ u64 fkey[16 * 65];
    if (tid < 64) strt[tid] = truths[n * 64 + tid];
    __syncthreads();
    int r = tid >> 2, sub = tid & 3, p = p0 + r;
    bool act = p < P;
    float vv[4] = {0, 0, 0, 0};
    u64 mykey = 0;
    if (act) {
        float4 pr = *(const float4*)(priors + (size_t)p * 4);
        float4 l  = *(const float4*)(loc + ((size_t)n * P + p) * 4);
        float cx = pr.x + l.x * 0.1f * pr.z;
        float cy = pr.y + l.y * 0.1f * pr.w;
        float w  = pr.z * fexp2(l.z * 0.2f * LOG2E);
        float h  = pr.w * fexp2(l.w * 0.2f * LOG2E);
        float bx1 = cx - w * 0.5f, by1 = cy - h * 0.5f;
        float bx2 = cx + w * 0.5f, by2 = cy + h * 0.5f;
        #pragma unroll
        for (int jj = 0; jj < 4; jj++) {
            int o = sub * 4 + jj;
            float v = iou_xyxy(strt[o * 4], strt[o * 4 + 1], strt[o * 4 + 2], strt[o * 4 + 3],
                               bx1, by1, bx2, by2);
            vv[jj] = v;
            u64 kk = ((u64)__float_as_uint(v) << 32) | (u32)(~(u32)o);
            if (kk > mykey) mykey = kk;
        }
    }
    { u64 t = __shfl_xor(mykey, 1, 64); if (t > mykey) mykey = t;
      t = __shfl_xor(mykey, 2, 64); if (t > mykey) mykey = t; }
    float m = keyval(mykey);
    if (act && sub == 0) ovkey[(size_t)n * P + p] = mykey;
    #pragma unroll
    for (int jj = 0; jj < 4; jj++) {
        int o = sub * 4 + jj;
        u64 kk = 0;
        if (act) kk = ((vv[jj] == m) ? ((u64)__float_as_uint(m) << 32) : 0ULL) | (u32)(~(u32)p);
        fkey[o * 65 + r] = kk;
    }
    __syncthreads();
    row_top15(fkey, cand, (size_t)n * 16, blockIdx.x, NBLK, tid);
}

// ---------- K2/K4: merge per-block top15 lists -> global top15, apply boosts ----------
__global__ __launch_bounds__(256) void k_merge_boost(
        const u64* __restrict__ cand, u64* __restrict__ keyarr,
        u32* __restrict__ plistP, u64* __restrict__ plistE, u32* __restrict__ pcnt,
        int record, int P, int NBLK) {
    extern __shared__ u64 sk[];
    int row = blockIdx.x, tid = threadIdx.x;
    int n = row >> 4, o = row & 15;
    int total = NBLK * 15;
    const u64* src = cand + (size_t)row * total;
    for (int i = tid; i < total; i += 256) sk[i] = src[i];
    __syncthreads();
    int l0 = tid, l1 = tid + 256;
    int h0 = 0, h1 = 0;
    __shared__ u64 wm[4];
    __shared__ u64 selk[15];
    __shared__ int snum;
    for (int j = 0; j < 15; j++) {
        u64 q0 = (l0 < NBLK && h0 < 15) ? sk[l0 * 15 + h0] : 0ULL;
        u64 q1 = (l1 < NBLK && h1 < 15) ? sk[l1 * 15 + h1] : 0ULL;
        u64 pr = q0 > q1 ? q0 : q1;
        u64 m = pr;
        #pragma unroll
        for (int s = 32; s >= 1; s >>= 1) { u64 t = __shfl_xor(m, s, 64); if (t > m) m = t; }
        if ((tid & 63) == 0) wm[tid >> 6] = m;
        __syncthreads();
        m = wm[0]; if (wm[1] > m) m = wm[1]; if (wm[2] > m) m = wm[2]; if (wm[3] > m) m = wm[3];
        if (m != 0ULL) {
            if (q0 == m) h0++; else if (q1 == m) h1++;
        }
        if (tid == 0) selk[j] = m;
        __syncthreads();
    }
    if (tid == 0) {
        float s = 0.0f;
        #pragma unroll
        for (int j = 0; j < 15; j++) s += keyval(selk[j]);
        int np = (int)s; if (np < 1) np = 1;
        snum = np;
    }
    __syncthreads();
    if (tid < 15 && tid < snum) {
        u64 k = selk[tid];
        u32 pidx = ~(u32)(k & 0xFFFFFFFFULL);
        if (pidx < (u32)P) {
            float v = keyval(k) + 3.0f;
            u64 bk = ((u64)__float_as_uint(v) << 32) | (u32)(~(u32)o);
            atomicMax(&keyarr[(size_t)n * P + pidx], bk);
            if (record) {
                u32 idx = atomicAdd(&pcnt[n], 1u);
                plistP[n * 256 + idx] = pidx;
                plistE[n * 256 + idx] = bk;
            }
        }
    }
}

// ---------- K2b: corrections for boosted anchors (target-class gfocal + posCount) ----
__global__ __launch_bounds__(256) void k_correct(
        const float* __restrict__ conf, const int* __restrict__ labels,
        const u64* __restrict__ ovkey, const u32* __restrict__ plistP,
        const u64* __restrict__ plistE, const u32* __restrict__ pcnt,
        double* __restrict__ accC, unsigned int* __restrict__ posCount, int P) {
    int n = blockIdx.x, tid = threadIdx.x;
    __shared__ int lab[16];
    if (tid < 16) lab[tid] = labels[n * 16 + tid];
    __syncthreads();
    int cnt = (int)pcnt[n];
    float dsum = 0.0f;
    int mypos = 0;
    for (int t = tid; t < cnt; t += 256) {
        u32 p = plistP[n * 256 + t];
        u64 bk = plistE[n * 256 + t];
        u64 k = ovkey[(size_t)n * P + p];
        if (k == bk) {                        // this entry owns the final key
            float v3 = keyval(k);
            float vt = v3 - 3.0f;
            if (vt > 0.0f) {
                mypos++;
                int o = (int)(~(u32)(k & 0xFFFFFFFFULL)) & 15;
                int tcls = lab[o];
                float lg = conf[((size_t)n * P + p) * 80 + tcls];
                float e  = fexp2(-fabsf(lg) * LOG2E);
                float ln1pe = flog2(1.0f + e) * LN2;
                float rc = frcp(1.0f + e);
                float sg = (lg >= 0.0f) ? rc : e * rc;
                float bce0 = fmaxf(lg, 0.0f) + ln1pe;
                float bce1 = fmaxf(lg, 0.0f) - lg * vt + ln1pe;
                float d1 = sg - vt;
                dsum += d1 * d1 * bce1 - sg * sg * bce0;
            }
        }
    }
    double dd = (double)dsum;
    long pp = mypos;
    #pragma unroll
    for (int s = 32; s > 0; s >>= 1) { dd += __shfl_down(dd, s, 64); pp += __shfl_down(pp, s, 64); }
    __shared__ double wd[4];
    __shared__ long wp[4];
    if ((tid & 63) == 0) { wd[tid >> 6] = dd; wp[tid >> 6] = pp; }
    __syncthreads();
    if (tid == 0) {
        double td = wd[0] + wd[1] + wd[2] + wd[3];
        long tp = wp[0] + wp[1] + wp[2] + wp[3];
        if (td != 0.0) atomicAdd(accC, td);
        if (tp) atomicAdd(posCount, (u32)tp);
    }
}

// ---------- K3: pure-stream conf pass (t=0 gfocal) + pred base/cands ----------
__global__ __launch_bounds__(256) void k_conf(
        const float* __restrict__ conf, const float* __restrict__ priors,
        const float* __restrict__ truths, const int* __restrict__ labels,
        u64* __restrict__ predkey, u64* __restrict__ cand,
        double* __restrict__ accC, int P, int NBLK) {
    int n = blockIdx.y, p0 = blockIdx.x * 64, tid = threadIdx.x;
    int r = tid >> 2, sub = tid & 3, p = p0 + r;
    bool act = p < P;

    // issue stream loads FIRST (in flight across the LDS setup barriers)
    float4 L0, L1, L2, L3, L4, prv;
    L0 = L1 = L2 = L3 = L4 = prv = make_float4(0.f, 0.f, 0.f, 0.f);
    if (act) {
        const float* rowp = conf + ((size_t)n * P + p) * 80 + sub * 4;
        L0 = *(const float4*)(rowp);
        L1 = *(const float4*)(rowp + 16);
        L2 = *(const float4*)(rowp + 32);
        L3 = *(const float4*)(rowp + 48);
        L4 = *(const float4*)(rowp + 64);
        prv = *(const float4*)(priors + (size_t)p * 4);
    }

    __shared__ float strt[64];
    __shared__ int   lab[16];
    __shared__ u32   smask[80];
    __shared__ float sglab[64][17];
    __shared__ u64   fkey[16 * 65];
    if (tid < 64) strt[tid] = truths[n * 64 + tid];
    if (tid < 80) smask[tid] = 0u;
    __syncthreads();
    if (tid < 16) {
        int lb = labels[n * 16 + tid];
        lab[tid] = lb;
        atomicOr(&smask[lb], 1u << tid);
    }
    __syncthreads();

    // register bitmask of which of my 20 classes are labels (20 batched LDS reads)
    u32 mybits = 0;
    #pragma unroll
    for (int k = 0; k < 5; k++) {
        #pragma unroll
        for (int j = 0; j < 4; j++) {
            if (smask[k * 16 + sub * 4 + j]) mybits |= 1u << (k * 4 + j);
        }
    }

    // ---- gfocal stream, t = 0 everywhere (corrections applied by k_correct)
    float lsum = 0.0f;
    if (act) {
        float lv[20] = {L0.x, L0.y, L0.z, L0.w, L1.x, L1.y, L1.z, L1.w,
                        L2.x, L2.y, L2.z, L2.w, L3.x, L3.y, L3.z, L3.w,
                        L4.x, L4.y, L4.z, L4.w};
        #pragma unroll
        for (int k = 0; k < 5; k++) {
            #pragma unroll
            for (int j = 0; j < 4; j++) {
                float lg = lv[k * 4 + j];
                float e  = fexp2(-fabsf(lg) * LOG2E);
                float ln1pe = flog2(1.0f + e) * LN2;
                float rc = frcp(1.0f + e);
                float sg = (lg >= 0.0f) ? rc : e * rc;
                lsum += sg * sg * (fmaxf(lg, 0.0f) + ln1pe);
                if (mybits & (1u << (k * 4 + j))) {      // rare
                    u32 m16 = smask[k * 16 + sub * 4 + j];
                    while (m16) {
                        int o = __ffs(m16) - 1;
                        sglab[r][o] = sg;
                        m16 &= m16 - 1;
                    }
                }
            }
        }
    }
    __syncthreads();

    // ---- pred path: 4 IoUs + 4 sglab reads per sub-lane
    float pv[4] = {0, 0, 0, 0};
    u64 pkey = 0;
    if (act) {
        float px1 = prv.x - prv.z * 0.5f, py1 = prv.y - prv.w * 0.5f;
        float px2 = prv.x + prv.z * 0.5f, py2 = prv.y + prv.w * 0.5f;
        #pragma unroll
        for (int jj = 0; jj < 4; jj++) {
            int o = sub * 4 + jj;
            float ov = iou_xyxy(strt[o * 4], strt[o * 4 + 1], strt[o * 4 + 2], strt[o * 4 + 3],
                                px1, py1, px2, py2);
            float pd = 0.0f;
            if (ov > 0.0f) {
                float pc = sglab[r][o];
                pd = fexp2((2.0f - pc) * 0.5f * flog2(ov));
            }
            pv[jj] = pd;
            u64 kk = ((u64)__float_as_uint(pd) << 32) | (u32)(~(u32)o);
            if (kk > pkey) pkey = kk;
        }
    }
    { u64 t = __shfl_xor(pkey, 1, 64); if (t > pkey) pkey = t;
      t = __shfl_xor(pkey, 2, 64); if (t > pkey) pkey = t; }
    float pm = keyval(pkey);
    if (act && sub == 0) predkey[(size_t)n * P + p] = pkey;

    #pragma unroll
    for (int jj = 0; jj < 4; jj++) {
        int o = sub * 4 + jj;
        u64 kk = 0;
        if (act) kk = ((pv[jj] == pm) ? ((u64)__float_as_uint(pm) << 32) : 0ULL) | (u32)(~(u32)p);
        fkey[o * 65 + r] = kk;
    }
    __syncthreads();
    row_top15(fkey, cand, (size_t)n * 16, blockIdx.x, NBLK, tid);

    // ---- block reduce gfocal partials
    #pragma unroll
    for (int s = 32; s > 0; s >>= 1) lsum += __shfl_down(lsum, s, 64);
    __shared__ float wsum[4];
    if ((tid & 63) == 0) wsum[tid >> 6] = lsum;
    __syncthreads();
    if (tid == 0) {
        double tot = (double)wsum[0] + (double)wsum[1] + (double)wsum[2] + (double)wsum[3];
        atomicAdd(accC, tot);
    }
}

// ---------- K5: localization loss from predkey ----------
__global__ __launch_bounds__(256) void k_loss_l(
        const u64* __restrict__ predkey, const float* __restrict__ loc,
        const float* __restrict__ priors, const float* __restrict__ truths,
        double* __restrict__ accL, double* __restrict__ accR, int P) {
    int n = blockIdx.y;
    int p = blockIdx.x * 256 + threadIdx.x;
    __shared__ float strt[64];
    if (threadIdx.x < 64) strt[threadIdx.x] = truths[n * 64 + threadIdx.x];
    __syncthreads();

    float r = 0.0f, contrib = 0.0f;
    if (p < P) {
        u64 k = predkey[(size_t)n * P + p];
        float pt = keyval(k);
        int best = (int)(~(u32)(k & 0xFFFFFFFFULL)) & 15;
        r = fmaxf(pt - 3.0f, 0.0f);
        if (r > 0.0f) {
            const float Bc   = (float)19.085536923187668;
            const float beta = 0.11f;
            float4 pr = *(const float4*)(priors + (size_t)p * 4);
            float tx1 = strt[best * 4],     ty1 = strt[best * 4 + 1];
            float tx2 = strt[best * 4 + 2], ty2 = strt[best * 4 + 3];
            float gcx = ((tx1 + tx2) * 0.5f - pr.x) / (0.1f * pr.z);
            float gcy = ((ty1 + ty2) * 0.5f - pr.y) / (0.1f * pr.w);
            float gw  = flog2((tx2 - tx1) / pr.z) * LN2 / 0.2f;
            float gh  = flog2((ty2 - ty1) / pr.w) * LN2 / 0.2f;
            float4 l  = *(const float4*)(loc + ((size_t)n * P + p) * 4);
            float tgt[4] = {gcx, gcy, gw, gh};
            float lvv[4] = {l.x, l.y, l.z, l.w};
            float s = 0.0f;
            #pragma unroll
            for (int j = 0; j < 4; j++) {
                float diff = fabsf(lvv[j] - tgt[j]);
                float bl;
                if (diff < beta) {
                    bl = 0.5f / Bc * (Bc * diff + 1.0f) * (flog2(1.0f + Bc * diff / beta) * LN2)
                         - 0.5f * diff;
                } else {
                    bl = 1.5f * diff + 1.5f / Bc - 0.5f * beta;
                }
                s += bl;
            }
            contrib = r * s;
        }
    }
    double dl = (double)contrib, dr = (double)r;
    for (int s = 32; s > 0; s >>= 1) { dl += __shfl_down(dl, s, 64); dr += __shfl_down(dr, s, 64); }
    __shared__ double bl_[4], br_[4];
    int wid = threadIdx.x >> 6;
    if ((threadIdx.x & 63) == 0) { bl_[wid] = dl; br_[wid] = dr; }
    __syncthreads();
    if (threadIdx.x == 0) {
        double tl  = bl_[0] + bl_[1] + bl_[2] + bl_[3];
        double tr2 = br_[0] + br_[1] + br_[2] + br_[3];
        atomicAdd(accL, tl);
        atomicAdd(accR, tr2);
    }
}

// ---------- K7: finalize ----------
__global__ void k_final(const double* accC, const double* accL, const double* accR,
                        const unsigned int* posCount, float* out) {
    if (threadIdx.x == 0) {
        unsigned int pc = *posCount;
        double npos = (double)(pc > 0u ? pc : 1u);
        double denom = 4.0 * (*accR);
        out[0] = (float)((*accL) / denom);
        out[1] = (float)((*accC) / npos);
    }
}

extern "C" void kernel_launch(void* const* d_in, const int* in_sizes, int n_in,
                              void* d_out, int out_size, void* d_ws, size_t ws_size,
                              hipStream_t stream) {
    const float* loc    = (const float*)d_in[0];
    const float* conf   = (const float*)d_in[1];
    const float* priors = (const float*)d_in[2];
    const float* truths = (const float*)d_in[3];
    const int*   labels = (const int*)d_in[4];

    int P = in_sizes[2] / 4;                 // 18000
    int N = in_sizes[0] / (P * 4);           // 32
    int NBLK = (P + 63) / 64;                // 282
    // C == 80, O == 16 assumed by kernel tiling

    char* ws = (char*)d_ws;
    double* accC = (double*)ws;
    double* accL = accC + 1;
    double* accR = accC + 2;
    unsigned int* posCount = (unsigned int*)(accC + 3);
    u32* pcnt   = (u32*)(ws + 64);                        // N counters
    u32* plistP = (u32*)(ws + 256);                       // N*256 u32
    u64* plistE = (u64*)(ws + 256 + (size_t)N * 256 * 4); // N*256 u64
    char* bulk  = ws + 256 + (size_t)N * 256 * 4 + (size_t)N * 256 * 8;
    u64* ovkey   = (u64*)bulk;                            // N*P
    u64* predkey = ovkey + (size_t)N * P;                 // N*P
    u64* cand    = predkey + (size_t)N * P;               // N*16*NBLK*15
    float* out = (float*)d_out;

    dim3 blk(256);
    dim3 gridB(NBLK, N);
    dim3 gridL((P + 255) / 256, N);
    size_t mergeLds = (size_t)NBLK * 15 * sizeof(u64);    // 33840 B

    k_zero<<<1, 64, 0, stream>>>(accC, accL, accR, posCount, pcnt, N);
    k_reg<<<gridB, blk, 0, stream>>>(loc, priors, truths, ovkey, cand, P, NBLK);
    k_merge_boost<<<N * 16, blk, mergeLds, stream>>>(cand, ovkey, plistP, plistE, pcnt,
                                                     1, P, NBLK);
    k_correct<<<N, blk, 0, stream>>>(conf, labels, ovkey, plistP, plistE, pcnt,
                                     accC, posCount, P);
    k_conf<<<gridB, blk, 0, stream>>>(conf, priors, truths, labels, predkey,
                                      cand, accC, P, NBLK);
    k_merge_boost<<<N * 16, blk, mergeLds, stream>>>(cand, predkey, plistP, plistE, pcnt,
                                                     0, P, NBLK);
    k_loss_l<<<gridL, blk, 0, stream>>>(predkey, loc, priors, truths, accL, accR, P);
    k_final<<<1, 1, 0, stream>>>(accC, accL, accR, posCount, out);
}